// Round 13
// baseline (354.613 us; speedup 1.0000x reference)
//
#include <hip/hip_runtime.h>
#include <hip/hip_bf16.h>

// ---------------------------------------------------------------------------
// GraphSAGE forward. GEMM: BM=32 x BN=256, NO K-tiling (R11 structure).
//   - A-tile = 32 rows x K = one CONTIGUOUS 32KB block, staged via plain
//     per-lane 16B loads + ds_write_b128 (R12: global_load_lds removed —
//     R11's multi-row load_lds staging was the only unproven construct in a
//     replay-only divergence; plain LDS ops have textbook barrier semantics).
//   - B (<=256KB) is L2-resident: read as MFMA fragments direct to regs.
//   - K-loop: no barriers, fully unrolled; 5 blocks/CU (20 waves) hide L2/HBM.
// Pipeline:
//   Wc=bf16(W_pre2@W_pre), bc; Acat[M,512]: cols0-255=mean1, 256-511=H2(->TR)
//   H2 = x @ Wc.T + bc (fp32 A: contiguous reg-load + cvt + swizzled ds_write)
//   mean1 = CSR-mean(H2); H3 = relu(Acat @ [Wl1|Wr1].T + bl1)
//   TR = H3 @ [Wl2;Wr2].T; out = l2norm(mean(T) + bl2 + R)
// ---------------------------------------------------------------------------

typedef __attribute__((ext_vector_type(4))) float f32x4;
typedef __attribute__((ext_vector_type(8))) short s8v;

__device__ __forceinline__ float bf2f(unsigned short u) {
  union { unsigned int i; float f; } v; v.i = ((unsigned int)u) << 16; return v.f;
}
__device__ __forceinline__ unsigned short f2bf(float f) {
  unsigned int u = __builtin_bit_cast(unsigned int, f);
  u += 0x7fffu + ((u >> 16) & 1u);          // round-to-nearest-even
  return (unsigned short)(u >> 16);
}

// ------------------------------ CSR build ----------------------------------
__global__ __launch_bounds__(256) void zero_int_kernel(int* __restrict__ p, int n) {
  int i = blockIdx.x * blockDim.x + threadIdx.x;
  const int stride = gridDim.x * blockDim.x;
  for (; i < n; i += stride) p[i] = 0;
}

__global__ __launch_bounds__(256) void count_kernel(const int* __restrict__ dst,
                                                    int* __restrict__ cnt, int E) {
  const int e = blockIdx.x * blockDim.x + threadIdx.x;
  if (e < E) atomicAdd(&cnt[dst[e]], 1);
}

__global__ __launch_bounds__(256) void scan_pass1(const int* __restrict__ cnt,
                                                  int* __restrict__ bsum, int M) {
  __shared__ int red[256];
  const int t = threadIdx.x;
  const int i = blockIdx.x * 256 + t;
  red[t] = (i < M) ? cnt[i] : 0;
  __syncthreads();
  for (int off = 128; off > 0; off >>= 1) {
    if (t < off) red[t] += red[t + off];
    __syncthreads();
  }
  if (t == 0) bsum[blockIdx.x] = red[0];
}

__global__ __launch_bounds__(256) void scan_pass2(const int* __restrict__ bsum,
    int* __restrict__ boff, int* __restrict__ rowptr, int nb, int M, int E) {
  __shared__ int buf[256];
  const int t = threadIdx.x;
  const int v = (t < nb) ? bsum[t] : 0;
  buf[t] = v;
  __syncthreads();
  for (int off = 1; off < 256; off <<= 1) {
    const int add = (t >= off) ? buf[t - off] : 0;
    __syncthreads();
    buf[t] += add;
    __syncthreads();
  }
  if (t < nb) boff[t] = buf[t] - v;
  if (t == 0) rowptr[M] = E;
}

__global__ __launch_bounds__(256) void scan_pass3(int* __restrict__ cnt,
    const int* __restrict__ boff, int* __restrict__ rowptr, int M) {
  __shared__ int buf[256];
  const int t = threadIdx.x;
  const int i = blockIdx.x * 256 + t;
  const int v = (i < M) ? cnt[i] : 0;
  buf[t] = v;
  __syncthreads();
  for (int off = 1; off < 256; off <<= 1) {
    const int add = (t >= off) ? buf[t - off] : 0;
    __syncthreads();
    buf[t] += add;
    __syncthreads();
  }
  if (i < M) {
    rowptr[i] = buf[t] - v + boff[blockIdx.x];
    cnt[i] = 0;   // reset for fill cursor
  }
}

__global__ __launch_bounds__(256) void fill_kernel(const int* __restrict__ src,
    const int* __restrict__ dst, const int* __restrict__ rowptr,
    int* __restrict__ cursor, unsigned short* __restrict__ eidx, int E) {
  const int e = blockIdx.x * blockDim.x + threadIdx.x;
  if (e >= E) return;
  const int d = dst[e];
  const int pos = rowptr[d] + atomicAdd(&cursor[d], 1);
  eidx[pos] = (unsigned short)src[e];
}

// --------------------- fused weight preparation ----------------------------
__global__ __launch_bounds__(256) void prep_kernel(const float* __restrict__ Wp,
    const float* __restrict__ Wp2, const float* __restrict__ bp,
    const float* __restrict__ bp2, const float* __restrict__ Wl1,
    const float* __restrict__ Wr1, const float* __restrict__ Wl2,
    const float* __restrict__ Wr2, unsigned short* __restrict__ Wc,
    float* __restrict__ bc, unsigned short* __restrict__ Bc1,
    unsigned short* __restrict__ Bc2) {
  const int b = blockIdx.x, t = threadIdx.x;
  if (b < 256) {
    __shared__ float wrow[256];
    wrow[t] = Wp2[b * 256 + t];
    __syncthreads();
    float a0 = 0.f, a1 = 0.f;
    for (int m = 0; m < 256; ++m) {
      const float w = wrow[m];
      a0 = fmaf(w, Wp[m * 512 + t], a0);
      a1 = fmaf(w, Wp[m * 512 + 256 + t], a1);
    }
    Wc[b * 512 + t] = f2bf(a0);
    Wc[b * 512 + 256 + t] = f2bf(a1);
  } else if (b == 256) {
    float s = 0.f;
    for (int m = 0; m < 256; ++m) s = fmaf(Wp2[t * 256 + m], bp[m], s);
    bc[t] = s + bp2[t];
  } else if (b < 769) {
    const int idx = (b - 257) * 256 + t;   // < 256*512
    const int o = idx >> 9, k = idx & 511;
    const float v = (k < 256) ? Wl1[o * 256 + k] : Wr1[o * 256 + (k - 256)];
    Bc1[idx] = f2bf(v);
  } else {
    const int idx = (b - 769) * 256 + t;   // < 256*256
    const int r = idx >> 8, k = idx & 255;
    const float v = (r < 128) ? Wl2[r * 256 + k] : Wr2[(r - 128) * 256 + k];
    Bc2[idx] = f2bf(v);
  }
}

// ---------------------------------------------------------------------------
// MFMA GEMM, BM=32 BN=256, no K-tiling. C[M,256] = act(A[M,K] @ B[256,K].T).
// 4 waves; wave w owns rows[0..32) x cols[w*64, w*64+64).
// A in LDS (32 x K bf16, 16B-slot swizzle phys = slot ^ (row&7)), staged by
// plain loads + ds_write; B fragments read directly from global (L2-hot).
// ---------------------------------------------------------------------------
template <int K, int ASTRIDE, int CSTRIDE, int CBASE, bool BIAS_EN, bool RELU_EN, bool A_FP32>
__global__ __launch_bounds__(256) void mfma_gemm(const void* __restrict__ Ap,
    const unsigned short* __restrict__ Bp, const float* __restrict__ bias,
    unsigned short* __restrict__ Cp, int M, int nwg) {
  constexpr int NC = K / 32;                 // MFMA k-chunks
  constexpr int ROWB = K * 2;                // bytes per LDS A-row
  constexpr int PITCH = 544;                 // epilogue image pitch
  constexpr int SMEM = (32 * ROWB > 32 * PITCH) ? 32 * ROWB : 32 * PITCH;
  __shared__ __align__(16) char smem[SMEM];

  // bijective XCD chunking (m204)
  const int xcd = blockIdx.x & 7, bidx = blockIdx.x >> 3;
  const int q = nwg >> 3, r7 = nwg & 7;
  const int wg = (xcd < r7 ? xcd * (q + 1) : r7 * (q + 1) + (xcd - r7) * q) + bidx;
  const int bm = wg * 32;

  const int t = threadIdx.x, w = t >> 6, l = t & 63;
  const int lane15 = l & 15, half = l >> 4;   // half in 0..3

  // ---- stage A (contiguous DRAM reads; swizzle folded into source addr) ----
  if constexpr (A_FP32) {
    // fp32 rows (2KB): lane covers floats [l*8, l*8+8) of its row ->
    // 16B bf16 = logical slot l -> phys slot l ^ (r&7).
#pragma unroll
    for (int b = 0; b < 2; ++b) {
      float4 f[4][2];
#pragma unroll
      for (int i = 0; i < 4; ++i) {
        const int r = w * 8 + b * 4 + i;
        const float* ar = (const float*)Ap + (size_t)min(bm + r, M - 1) * ASTRIDE;
        f[i][0] = *(const float4*)(ar + l * 8);
        f[i][1] = *(const float4*)(ar + l * 8 + 4);
      }
#pragma unroll
      for (int i = 0; i < 4; ++i) {
        const int r = w * 8 + b * 4 + i;
        s8v pk;
        pk[0] = (short)f2bf(f[i][0].x); pk[1] = (short)f2bf(f[i][0].y);
        pk[2] = (short)f2bf(f[i][0].z); pk[3] = (short)f2bf(f[i][0].w);
        pk[4] = (short)f2bf(f[i][1].x); pk[5] = (short)f2bf(f[i][1].y);
        pk[6] = (short)f2bf(f[i][1].z); pk[7] = (short)f2bf(f[i][1].w);
        *(s8v*)(smem + r * ROWB + ((l ^ (r & 7)) << 4)) = pk;
      }
    }
  } else if constexpr (K == 512) {
    // 1KB rows: one wave covers one full row per step (contiguous 1KB reads)
    s8v v[8];
#pragma unroll
    for (int j = 0; j < 8; ++j) {
      const int r = w * 8 + j;
      v[j] = *(const s8v*)((const unsigned short*)Ap +
          (size_t)min(bm + r, M - 1) * ASTRIDE + ((l ^ (r & 7)) * 8));
    }
#pragma unroll
    for (int j = 0; j < 8; ++j) {
      const int r = w * 8 + j;
      *(s8v*)(smem + r * ROWB + l * 16) = v[j];
    }
  } else {
    // 512B rows: one wave covers two consecutive rows per step
    s8v v[4];
#pragma unroll
    for (int j = 0; j < 4; ++j) {
      const int r0 = w * 8 + 2 * j;
      const int rl = r0 + (l >> 5);
      v[j] = *(const s8v*)((const unsigned short*)Ap +
          (size_t)min(bm + rl, M - 1) * ASTRIDE + (((l & 31) ^ (rl & 7)) * 8));
    }
#pragma unroll
    for (int j = 0; j < 4; ++j) {
      const int r0 = w * 8 + 2 * j;
      *(s8v*)(smem + r0 * ROWB + l * 16) = v[j];
    }
  }
  __syncthreads();

  // ---- compute: K fully unrolled, no barriers; B frags from L2 ----
  const int rA0 = lane15, rA1 = 16 + lane15;
  const int ro0 = rA0 * ROWB, ro1 = rA1 * ROWB;
  const int rx0 = rA0 & 7, rx1 = rA1 & 7;
  const unsigned short* bpn0 = Bp + (size_t)(w * 64 + 0 * 16 + lane15) * K + half * 8;
  const unsigned short* bpn1 = Bp + (size_t)(w * 64 + 1 * 16 + lane15) * K + half * 8;
  const unsigned short* bpn2 = Bp + (size_t)(w * 64 + 2 * 16 + lane15) * K + half * 8;
  const unsigned short* bpn3 = Bp + (size_t)(w * 64 + 3 * 16 + lane15) * K + half * 8;

  f32x4 acc[2][4];
#pragma unroll
  for (int i = 0; i < 2; ++i)
#pragma unroll
    for (int j = 0; j < 4; ++j) acc[i][j] = f32x4{0.f, 0.f, 0.f, 0.f};

#pragma unroll
  for (int kc = 0; kc < NC; ++kc) {
    const s8v bv0 = *(const s8v*)(bpn0 + kc * 32);
    const s8v bv1 = *(const s8v*)(bpn1 + kc * 32);
    const s8v bv2 = *(const s8v*)(bpn2 + kc * 32);
    const s8v bv3 = *(const s8v*)(bpn3 + kc * 32);
    const int sl = kc * 4 + half;
    const s8v a0 = *(const s8v*)(smem + ro0 + ((sl ^ rx0) << 4));
    const s8v a1 = *(const s8v*)(smem + ro1 + ((sl ^ rx1) << 4));
    acc[0][0] = __builtin_amdgcn_mfma_f32_16x16x32_bf16(a0, bv0, acc[0][0], 0, 0, 0);
    acc[0][1] = __builtin_amdgcn_mfma_f32_16x16x32_bf16(a0, bv1, acc[0][1], 0, 0, 0);
    acc[0][2] = __builtin_amdgcn_mfma_f32_16x16x32_bf16(a0, bv2, acc[0][2], 0, 0, 0);
    acc[0][3] = __builtin_amdgcn_mfma_f32_16x16x32_bf16(a0, bv3, acc[0][3], 0, 0, 0);
    acc[1][0] = __builtin_amdgcn_mfma_f32_16x16x32_bf16(a1, bv0, acc[1][0], 0, 0, 0);
    acc[1][1] = __builtin_amdgcn_mfma_f32_16x16x32_bf16(a1, bv1, acc[1][1], 0, 0, 0);
    acc[1][2] = __builtin_amdgcn_mfma_f32_16x16x32_bf16(a1, bv2, acc[1][2], 0, 0, 0);
    acc[1][3] = __builtin_amdgcn_mfma_f32_16x16x32_bf16(a1, bv3, acc[1][3], 0, 0, 0);
  }

  // ---- epilogue: LDS image [32][PITCH] -> coalesced 512B-row stores ----
  float bias_l[4];
  if (BIAS_EN) {
#pragma unroll
    for (int ns = 0; ns < 4; ++ns) bias_l[ns] = bias[w * 64 + ns * 16 + lane15];
  }
  __syncthreads();           // all waves' A reads complete; LDS reusable
#pragma unroll
  for (int ms = 0; ms < 2; ++ms)
#pragma unroll
    for (int ns = 0; ns < 4; ++ns) {
      f32x4 v = acc[ms][ns];
      if (BIAS_EN) {
#pragma unroll
        for (int rg = 0; rg < 4; ++rg) v[rg] += bias_l[ns];
      }
      if (RELU_EN) {
#pragma unroll
        for (int rg = 0; rg < 4; ++rg) v[rg] = fmaxf(v[rg], 0.f);
      }
      const int colb = (w * 64 + ns * 16 + lane15) * 2;
#pragma unroll
      for (int rg = 0; rg < 4; ++rg) {
        const int row = ms * 16 + half * 4 + rg;
        *(unsigned short*)(smem + row * PITCH + colb) = f2bf(v[rg]);
      }
    }
  __syncthreads();
  // 32 rows x 512B; each wave-instruction stores 1KB contiguous (2 rows)
#pragma unroll
  for (int p = 0; p < 4; ++p) {
    const int lr = p * 8 + (t >> 5);
    const int grow = bm + lr;
    if (grow < M) {
      const s8v val = *(const s8v*)(smem + lr * PITCH + (t & 31) * 16);
      *(s8v*)(Cp + (size_t)grow * CSTRIDE + CBASE + (t & 31) * 8) = val;
    }
  }
}

// ------------------------------- gathers -----------------------------------
// one wave per node: mean of in-neighbor H2 rows (bf16, Acat cols 256..511)
__global__ __launch_bounds__(256) void gather_mean256_kernel(
    unsigned short* __restrict__ Acat, const int* __restrict__ rowptr,
    const unsigned short* __restrict__ eidx, int M) {
  const int node = blockIdx.x * 4 + (threadIdx.x >> 6);
  if (node >= M) return;
  const int lane = threadIdx.x & 63;
  const int c4 = lane * 4;
  const int beg = rowptr[node], end = rowptr[node + 1];
  float a0 = 0.f, a1 = 0.f, a2 = 0.f, a3 = 0.f;
  int j = beg;
  for (; j + 3 < end; j += 4) {
    const size_t s0 = eidx[j], s1 = eidx[j + 1], s2 = eidx[j + 2], s3 = eidx[j + 3];
    const ushort4 v0 = *(const ushort4*)(Acat + s0 * 512 + 256 + c4);
    const ushort4 v1 = *(const ushort4*)(Acat + s1 * 512 + 256 + c4);
    const ushort4 v2 = *(const ushort4*)(Acat + s2 * 512 + 256 + c4);
    const ushort4 v3 = *(const ushort4*)(Acat + s3 * 512 + 256 + c4);
    a0 += (bf2f(v0.x) + bf2f(v1.x)) + (bf2f(v2.x) + bf2f(v3.x));
    a1 += (bf2f(v0.y) + bf2f(v1.y)) + (bf2f(v2.y) + bf2f(v3.y));
    a2 += (bf2f(v0.z) + bf2f(v1.z)) + (bf2f(v2.z) + bf2f(v3.z));
    a3 += (bf2f(v0.w) + bf2f(v1.w)) + (bf2f(v2.w) + bf2f(v3.w));
  }
  for (; j < end; ++j) {
    const size_t s0 = eidx[j];
    const ushort4 v0 = *(const ushort4*)(Acat + s0 * 512 + 256 + c4);
    a0 += bf2f(v0.x); a1 += bf2f(v0.y); a2 += bf2f(v0.z); a3 += bf2f(v0.w);
  }
  const float inv = 1.0f / fmaxf((float)(end - beg), 1.0f);
  ushort4 o;
  o.x = f2bf(a0 * inv); o.y = f2bf(a1 * inv);
  o.z = f2bf(a2 * inv); o.w = f2bf(a3 * inv);
  *(ushort4*)(Acat + (size_t)node * 512 + c4) = o;
}

// one wave per node: v = mean(T[src]) + bl2 + R ; out = v / max(||v||,1e-12)
__global__ __launch_bounds__(256) void gather_finalize_kernel(
    const unsigned short* __restrict__ Acat, const int* __restrict__ rowptr,
    const unsigned short* __restrict__ eidx, const float* __restrict__ bl2,
    float* __restrict__ out, int M) {
  const int node = blockIdx.x * 4 + (threadIdx.x >> 6);
  if (node >= M) return;
  const int lane = threadIdx.x & 63;
  const int c2 = lane * 2;
  const int beg = rowptr[node], end = rowptr[node + 1];
  float ax = 0.f, ay = 0.f;
  int j = beg;
  for (; j + 3 < end; j += 4) {
    const size_t s0 = eidx[j], s1 = eidx[j + 1], s2 = eidx[j + 2], s3 = eidx[j + 3];
    const ushort2 v0 = *(const ushort2*)(Acat + s0 * 512 + 256 + c2);
    const ushort2 v1 = *(const ushort2*)(Acat + s1 * 512 + 256 + c2);
    const ushort2 v2 = *(const ushort2*)(Acat + s2 * 512 + 256 + c2);
    const ushort2 v3 = *(const ushort2*)(Acat + s3 * 512 + 256 + c2);
    ax += (bf2f(v0.x) + bf2f(v1.x)) + (bf2f(v2.x) + bf2f(v3.x));
    ay += (bf2f(v0.y) + bf2f(v1.y)) + (bf2f(v2.y) + bf2f(v3.y));
  }
  for (; j < end; ++j) {
    const size_t s0 = eidx[j];
    const ushort2 v0 = *(const ushort2*)(Acat + s0 * 512 + 256 + c2);
    ax += bf2f(v0.x); ay += bf2f(v0.y);
  }
  const float inv = 1.0f / fmaxf((float)(end - beg), 1.0f);
  const ushort2 rr = *(const ushort2*)(Acat + (size_t)node * 512 + 384 + c2);
  const float2 b = *(const float2*)&bl2[c2];
  const float vx = fmaf(ax, inv, b.x) + bf2f(rr.x);
  const float vy = fmaf(ay, inv, b.y) + bf2f(rr.y);
  float ss = vx * vx + vy * vy;
#pragma unroll
  for (int off = 32; off > 0; off >>= 1) ss += __shfl_xor(ss, off);
  const float rn = 1.0f / fmaxf(sqrtf(ss), 1e-12f);
  *(float2*)&out[(size_t)node * 128 + c2] = make_float2(vx * rn, vy * rn);
}

// ---------------------------------------------------------------------------
extern "C" void kernel_launch(void* const* d_in, const int* in_sizes, int n_in,
                              void* d_out, int out_size, void* d_ws, size_t ws_size,
                              hipStream_t stream) {
  const float* x      = (const float*)d_in[0];
  const int*   ei     = (const int*)d_in[1];
  const float* W_pre  = (const float*)d_in[2];
  const float* b_pre  = (const float*)d_in[3];
  const float* W_pre2 = (const float*)d_in[4];
  const float* b_pre2 = (const float*)d_in[5];
  const float* Wl1    = (const float*)d_in[6];
  const float* bl1    = (const float*)d_in[7];
  const float* Wr1    = (const float*)d_in[8];
  const float* Wl2    = (const float*)d_in[9];
  const float* bl2    = (const float*)d_in[10];
  const float* Wr2    = (const float*)d_in[11];
  float* out = (float*)d_out;

  const int M = in_sizes[0] / 512;  // 50000
  const int E = in_sizes[1] / 2;    // 800000
  const int* src = ei;
  const int* dst = ei + E;

  // workspace: Acat bf16[M*512] | H3 bf16[M*256] | Wc[256*512] | Bc1[256*512]
  //   | Bc2[256*256] | bc f32[256] | rowptr[M+1] | cnt[M] | bsum | boff |
  //   eidx ushort[E]   (~80 MB)
  char* p = (char*)d_ws;
  unsigned short* Acat = (unsigned short*)p; p += (size_t)M * 512 * 2;
  unsigned short* H3   = (unsigned short*)p; p += (size_t)M * 256 * 2;
  unsigned short* Wc   = (unsigned short*)p; p += 256 * 512 * 2;
  unsigned short* Bc1  = (unsigned short*)p; p += 256 * 512 * 2;
  unsigned short* Bc2  = (unsigned short*)p; p += 256 * 256 * 2;
  float* bc   = (float*)p; p += 256 * 4;
  int* rowptr = (int*)p;   p += (size_t)(M + 1) * 4;
  int* cnt    = (int*)p;   p += (size_t)M * 4;
  int* bsum   = (int*)p;   p += 256 * 4;
  int* boff   = (int*)p;   p += 256 * 4;
  unsigned short* eidx = (unsigned short*)p;

  const int eblk = (E + 255) / 256;
  const int nb   = (M + 255) / 256;        // 196
  const int nwg  = (M + 31) / 32;          // 1563 tiles (BM=32, BN=256 full)
  const int nblk = (M + 3) / 4;

  // CSR build
  zero_int_kernel<<<256, 256, 0, stream>>>(cnt, M);
  count_kernel<<<eblk, 256, 0, stream>>>(dst, cnt, E);
  scan_pass1<<<nb, 256, 0, stream>>>(cnt, bsum, M);
  scan_pass2<<<1, 256, 0, stream>>>(bsum, boff, rowptr, nb, M, E);
  scan_pass3<<<nb, 256, 0, stream>>>(cnt, boff, rowptr, M);
  fill_kernel<<<eblk, 256, 0, stream>>>(src, dst, rowptr, cnt, eidx, E);

  // fused weight prep
  prep_kernel<<<1025, 256, 0, stream>>>(W_pre, W_pre2, b_pre, b_pre2,
                                        Wl1, Wr1, Wl2, Wr2, Wc, bc, Bc1, Bc2);

  // H2 = x @ Wc.T + bc  -> Acat cols 256..511 (fp32 A fused conversion)
  mfma_gemm<512, 512, 512, 256, true, false, true>
      <<<nwg, 256, 0, stream>>>(x, Wc, bc, Acat, M, nwg);
  // mean1 -> Acat cols 0..255
  gather_mean256_kernel<<<nblk, 256, 0, stream>>>(Acat, rowptr, eidx, M);
  // H3 = relu(Acat @ Bc1.T + bl1)
  mfma_gemm<512, 512, 256, 0, true, true, false>
      <<<nwg, 256, 0, stream>>>(Acat, Bc1, bl1, H3, M, nwg);
  // TR = H3 @ Bc2.T -> Acat cols 256..511 (H2 dead)
  mfma_gemm<256, 256, 512, 256, false, false, false>
      <<<nwg, 256, 0, stream>>>(H3, Bc2, nullptr, Acat, M, nwg);
  // out = l2norm(mean(T) + bl2 + R)
  gather_finalize_kernel<<<nblk, 256, 0, stream>>>(Acat, rowptr, eidx, bl2, out, M);
}